// Round 6
// baseline (190.266 us; speedup 1.0000x reference)
//
#include <hip/hip_runtime.h>

#define NS 32768
#define NC 395
#define FD 512
#define NEL (NC * FD)

#define RS 16                  // row splits
#define ROWS_PB (NS / RS)      // 2048 rows per block
#define CT 8                   // column tiles (64 floats each)
#define COLS 64
#define CF4 16                 // float4 per column tile
#define ASTR 68                // acc stride in floats (272B: 16B-aligned, odd*4 bank phase)
#define NW 8                   // waves per block
#define WCAP 224               // per-wave packed list capacity (mean 128, +8.7 sigma)

// Static device scratch — every slot rewritten each call.
__device__ float g_part[2 * RS * NC * FD];   // [mod][rs][cls][FD] 25.9 MB
__device__ int   g_hist[RS * NC];

// ---------------------------------------------------------------------------
// K1: streaming segment-sum, no atomics, no dedup, no conflicts BY DESIGN.
// Block = (rs, mod, ct, cg): rows [rs*2048,+2048) x cols [ct*64,+64) x class
// half cg. Wave w owns a CONTIGUOUS class range of its half; its rows are
// two-pass ballot-compacted into 4 sub-lists keyed by (class & 3), sharing
// one 224-entry buffer. A load group = one row from each sub-list (quad
// r=lane>>4, c4=lane&15): 4 rows x 256B contiguous = 1KB per dwordx4 instr.
// Group classes are DISTINCT (different residues) => single plain b128 RMW
// pass, no serialization. acc stride 68 floats => bank phase (cls+c4)&7;
// distinct residues mod 4 => never equal mod 8 => <=2-way (free). Empty
// slots exec-masked (no bandwidth). 4 groups in flight per wave.
__global__ __launch_bounds__(512, 4)
void k_stream(const float* __restrict__ m1, const float* __restrict__ m2,
              const int* __restrict__ targets, float* __restrict__ out)
{
    const int bid = blockIdx.x;
    const int cg  = bid & 1;
    const int ct  = (bid >> 1) & 7;
    const int mod = (bid >> 4) & 1;
    const int rs  = bid >> 5;
    const int t   = threadIdx.x;
    const int w   = t >> 6;
    const int lane = t & 63;
    const int r    = lane >> 4;       // quad 0..3 = sub-list id
    const int c4   = lane & 15;       // float4 col within tile

    const int cb  = cg ? 198 : 0;     // class-half base
    const int nch = cg ? 197 : 198;   // classes in this half

    __shared__ float acc[198 * ASTR];     // 53,856 B
    __shared__ int   lists[NW * WCAP];    //  7,168 B   (61,024 total)

    for (int i = t; i < 198 * ASTR; i += 512) acc[i] = 0.f;
    if (bid == 0 && t == 0) out[0] = 0.f;   // zero before k_loss

    // wave-owned contiguous class range [lo, hi)
    const int lo = cb + (w * nch) / 8;
    const int hi = cb + ((w + 1) * nch) / 8;

    const int* tgt = targets + rs * ROWS_PB;   // 8 KB, L1/L2-hot
    int* wlist = &lists[w * WCAP];

    // ---- pass 1: per-residue counts (no atomics) ----
    int n0 = 0, n1 = 0, n2 = 0, n3 = 0;
    for (int it = 0; it < ROWS_PB / 64; ++it) {
        int c = tgt[it * 64 + lane];
        bool mine = (c >= lo) && (c < hi);
        n0 += (int)__popcll(__ballot(mine && ((c & 3) == 0)));
        n1 += (int)__popcll(__ballot(mine && ((c & 3) == 1)));
        n2 += (int)__popcll(__ballot(mine && ((c & 3) == 2)));
        n3 += (int)__popcll(__ballot(mine && ((c & 3) == 3)));
    }
    const int b0 = 0, b1 = n0, b2 = n0 + n1, b3 = n0 + n1 + n2;

    // ---- pass 2: scatter into packed sub-lists (entry = idx | cls<<16) ----
    {
        int cur0 = b0, cur1 = b1, cur2 = b2, cur3 = b3;
        for (int it = 0; it < ROWS_PB / 64; ++it) {
            int idx = it * 64 + lane;
            int c = tgt[idx];
            bool mine = (c >= lo) && (c < hi);
            unsigned long long below = (1ull << lane) - 1ull;
#define SCAT(K, CUR)                                                     \
            {   unsigned long long m_ = __ballot(mine && ((c & 3) == K));\
                if (mine && ((c & 3) == K)) {                            \
                    int p_ = CUR + (int)__popcll(m_ & below);            \
                    if (p_ < WCAP) wlist[p_] = idx | (c << 16);          \
                }                                                        \
                CUR += (int)__popcll(m_);                                \
            }
            SCAT(0, cur0) SCAT(1, cur1) SCAT(2, cur2) SCAT(3, cur3)
#undef SCAT
        }
    }
    __syncthreads();   // acc zero-init + all wave lists complete

    // quad-private base/count (defensive clamp; unreachable for this data)
    int qb = (r == 0) ? b0 : (r == 1) ? b1 : (r == 2) ? b2 : b3;
    int qn = (r == 0) ? n0 : (r == 1) ? n1 : (r == 2) ? n2 : n3;
    if (qb > WCAP) qb = WCAP;
    if (qb + qn > WCAP) qn = WCAP - qb;
    const int ng = max(max(n0, n1), max(n2, n3));   // wave-uniform group count

    // ---- main loop: 1KB per load instr (4 rows x 256B), 4 groups in flight ----
    const float4* sp = reinterpret_cast<const float4*>(mod ? m2 : m1)
                     + (size_t)rs * ROWS_PB * (FD / 4) + ct * CF4 + c4;

#define LOADG(CLS, V, G)                                                 \
    {   int g_ = (G);                                                    \
        CLS = -1; V = make_float4(0.f, 0.f, 0.f, 0.f);                   \
        if (g_ < qn) {                  /* quad-uniform mask */          \
            int e_ = wlist[qb + g_];                                     \
            CLS = e_ >> 16;                                              \
            V = sp[(e_ & 0x7FF) * 128];  /* 256B contiguous per row */   \
        }                                                                \
    }

#define RMWG(CLS, V)                                                     \
    if (CLS >= 0) {                                                      \
        float* ap = &acc[(CLS - cb) * ASTR + c4 * 4];                    \
        float4 o_ = *reinterpret_cast<float4*>(ap);                      \
        o_.x += V.x; o_.y += V.y; o_.z += V.z; o_.w += V.w;              \
        *reinterpret_cast<float4*>(ap) = o_;                             \
    }

    int cls0, cls1, cls2, cls3, cn0, cn1, cn2, cn3;
    float4 v0, v1, v2, v3, u0, u1, u2, u3;

    LOADG(cls0, v0, 0) LOADG(cls1, v1, 1) LOADG(cls2, v2, 2) LOADG(cls3, v3, 3)
    const int nbat = (ng + 3) >> 2;
    for (int b = 1; b < nbat; ++b) {
        int gb = b << 2;
        LOADG(cn0, u0, gb)     LOADG(cn1, u1, gb + 1)
        LOADG(cn2, u2, gb + 2) LOADG(cn3, u3, gb + 3)
        RMWG(cls0, v0) RMWG(cls1, v1) RMWG(cls2, v2) RMWG(cls3, v3)
        cls0 = cn0; v0 = u0; cls1 = cn1; v1 = u1;
        cls2 = cn2; v2 = u2; cls3 = cn3; v3 = u3;
    }
    RMWG(cls0, v0) RMWG(cls1, v1) RMWG(cls2, v2) RMWG(cls3, v3)
#undef LOADG
#undef RMWG
    __syncthreads();

    // ---- writeout: acc -> g_part[(mod*RS+rs)][cb+cls][ct*64..] ----
    float4* dst = reinterpret_cast<float4*>(g_part)
                + (size_t)(mod * RS + rs) * (NEL / 4) + ct * CF4;
    for (int i = t; i < nch * CF4; i += 512) {
        int cl = i >> 4, cf = i & 15;
        float4 vv = *reinterpret_cast<float4*>(&acc[cl * ASTR + cf * 4]);
        dst[(size_t)(cb + cl) * (FD / 4) + cf] = vv;
    }

    // ---- fold histogram: one block per row-split (LDS reused) ----
    if (ct == 0 && mod == 0 && cg == 0) {  // block-uniform: barriers legal
        __syncthreads();
        int* h = reinterpret_cast<int*>(acc);
        for (int i = t; i < NC; i += 512) h[i] = 0;
        __syncthreads();
        for (int i = t; i < ROWS_PB; i += 512) atomicAdd(&h[tgt[i]], 1);
        __syncthreads();
        for (int i = t; i < NC; i += 512) g_hist[rs * NC + i] = h[i];
    }
}

// ---------------------------------------------------------------------------
__device__ __forceinline__ float smooth_l1(float d) {
    d = fabsf(d);
    return d < 1.0f ? 0.5f * d * d : d - 0.5f;
}

__device__ __forceinline__ void f4add(float4& a, const float4 b) {
    a.x += b.x; a.y += b.y; a.z += b.z; a.w += b.w;
}

// K2: combine RS partials per modality, SmoothL1 weighted by count, reduce.
__global__ __launch_bounds__(256)
void k_loss(const float* __restrict__ centers, float* __restrict__ out) {
    __shared__ float scnt[NC];
    int t = threadIdx.x;
    for (int c = t; c < NC; c += 256) {
        int s = 0;
        #pragma unroll
        for (int k = 0; k < RS; ++k) s += g_hist[k * NC + c];
        scnt[c] = (float)s;
    }
    __syncthreads();

    const float4* ctr4  = reinterpret_cast<const float4*>(centers);
    const float4* part4 = reinterpret_cast<const float4*>(g_part);
    const int NE4 = NEL / 4;          // 50560
    float val = 0.f;
    for (int g = blockIdx.x * 256 + t; g < NE4; g += gridDim.x * 256) {
        int cls = g >> 7;             // 128 float4 per class
        float cnt = scnt[cls];
        if (cnt > 0.f) {
            float4 s1 = make_float4(0,0,0,0), s2 = make_float4(0,0,0,0);
            #pragma unroll
            for (int k = 0; k < RS; ++k) {
                f4add(s1, part4[(size_t)k        * NE4 + g]);
                f4add(s2, part4[(size_t)(RS + k) * NE4 + g]);
            }
            float4 c4 = ctr4[g];
            float inv = 1.f / cnt;
            val += cnt * (smooth_l1(s1.x * inv - c4.x) + smooth_l1(s2.x * inv - c4.x)
                        + smooth_l1(s1.y * inv - c4.y) + smooth_l1(s2.y * inv - c4.y)
                        + smooth_l1(s1.z * inv - c4.z) + smooth_l1(s2.z * inv - c4.z)
                        + smooth_l1(s1.w * inv - c4.w) + smooth_l1(s2.w * inv - c4.w));
        }
    }

    for (int off = 32; off > 0; off >>= 1)
        val += __shfl_down(val, off, 64);
    __shared__ float wsum[4];
    int lane = t & 63, wid = t >> 6;
    if (lane == 0) wsum[wid] = val;
    __syncthreads();
    if (t == 0) {
        float sm = wsum[0] + wsum[1] + wsum[2] + wsum[3];
        atomicAdd(out, sm * 5.9604644775390625e-08f);  // 1/(N*D) = 2^-24
    }
}

extern "C" void kernel_launch(void* const* d_in, const int* in_sizes, int n_in,
                              void* d_out, int out_size, void* d_ws, size_t ws_size,
                              hipStream_t stream) {
    const float* m1 = (const float*)d_in[0];
    const float* m2 = (const float*)d_in[1];
    const float* centers = (const float*)d_in[2];
    const int* targets = (const int*)d_in[3];
    float* out = (float*)d_out;

    k_stream<<<RS * 2 * CT * 2, 512, 0, stream>>>(m1, m2, targets, out);
    k_loss<<<400, 256, 0, stream>>>(centers, out);
}

// Round 7
// 164.894 us; speedup vs baseline: 1.1539x; 1.1539x over previous
//
#include <hip/hip_runtime.h>

#define NS 32768
#define NC 395
#define FD 512
#define NEL (NC * FD)
#define HALF (NS / 2)          // 16384 targets scanned per block
#define SCAP 2048              // sidx capacity (per-(class,half) count ~42, 27x margin)

// Static device scratch — every slot rewritten each call.
__device__ float g_sum[2 * 2 * NC * FD];   // [half][mod][cls][FD] = 3.2 MB
__device__ int   g_cnt[2 * NC];

// ---------------------------------------------------------------------------
__device__ __forceinline__ void f4add(float4& a, const float4 b) {
    a.x += b.x; a.y += b.y; a.z += b.z; a.w += b.w;
}

// K1: one block per (class, row-half). Scan: 16 hoisted int4 loads/thread in
// two vmcnt rounds, LDS compaction (round-0 pattern, proven fast). Gather:
// 4 waves = 2 per modality; within a modality the two waves take even/odd
// matches and each LANE covers a full 2KB row (two float4 at lane, lane+64).
// ~21 rows/wave (4x round-0) so the 12-load 6-row pipeline actually cycles.
// Writes FINAL per-(half,mod,class) sums - no split partials.
__global__ __launch_bounds__(256)
void k_gather(const float4* __restrict__ m1, const float4* __restrict__ m2,
              const int* __restrict__ targets, float* __restrict__ out)
{
    const int c   = blockIdx.x >> 1;
    const int h   = blockIdx.x & 1;
    const int tid = threadIdx.x;

    if (blockIdx.x == 0 && tid == 0) out[0] = 0.0f;  // ordered before k_loss

    __shared__ int sidx[SCAP];        // 8 KB
    __shared__ int scnt;
    __shared__ float4 cmb[2][128];    // wave-pair combine buffer (4 KB)

    // ---- scan phase: 16384 targets, 16 int4/thread in two rounds ----
    const int4* t4 = reinterpret_cast<const int4*>(targets + h * HALF);
    int4 a0 = t4[tid          ], a1 = t4[tid +  1 * 256],
         a2 = t4[tid + 2 * 256], a3 = t4[tid +  3 * 256],
         a4 = t4[tid + 4 * 256], a5 = t4[tid +  5 * 256],
         a6 = t4[tid + 6 * 256], a7 = t4[tid +  7 * 256];
    if (tid == 0) scnt = 0;
    __syncthreads();
    int4 b0 = t4[tid +  8 * 256], b1 = t4[tid +  9 * 256],
         b2 = t4[tid + 10 * 256], b3 = t4[tid + 11 * 256],
         b4 = t4[tid + 12 * 256], b5 = t4[tid + 13 * 256],
         b6 = t4[tid + 14 * 256], b7 = t4[tid + 15 * 256];

#define CHK(V, K)                                                           \
    {   int ib = h * HALF + 4 * (tid + (K) * 256);                          \
        if (V.x == c) { int p = atomicAdd(&scnt, 1); if (p < SCAP) sidx[p] = ib;     } \
        if (V.y == c) { int p = atomicAdd(&scnt, 1); if (p < SCAP) sidx[p] = ib + 1; } \
        if (V.z == c) { int p = atomicAdd(&scnt, 1); if (p < SCAP) sidx[p] = ib + 2; } \
        if (V.w == c) { int p = atomicAdd(&scnt, 1); if (p < SCAP) sidx[p] = ib + 3; } }
    CHK(a0, 0) CHK(a1, 1) CHK(a2, 2)  CHK(a3, 3)
    CHK(a4, 4) CHK(a5, 5) CHK(a6, 6)  CHK(a7, 7)
    CHK(b0, 8) CHK(b1, 9) CHK(b2, 10) CHK(b3, 11)
    CHK(b4,12) CHK(b5,13) CHK(b6, 14) CHK(b7, 15)
#undef CHK
    __syncthreads();
    int cnt = scnt; if (cnt > SCAP) cnt = SCAP;

    // ---- gather phase ----
    const int wid  = tid >> 6;      // wave 0..3
    const int mod  = wid >> 1;      // modality (wave-uniform)
    const int par  = wid & 1;       // even/odd match subset (wave-uniform)
    const int lane = tid & 63;
    const float4* src = mod ? m2 : m1;

    float4 z = make_float4(0.f, 0.f, 0.f, 0.f);
    float4 aA0 = z, aB0 = z, aA1 = z, aB1 = z, aA2 = z, aB2 = z;

    int j = par;
    // 6 rows per iteration (stride 2 within this wave), 12 loads in flight.
    for (; j + 10 < cnt; j += 12) {
        const float4* p0 = src + (size_t)sidx[j]      * 128;
        const float4* p1 = src + (size_t)sidx[j +  2] * 128;
        const float4* p2 = src + (size_t)sidx[j +  4] * 128;
        const float4* p3 = src + (size_t)sidx[j +  6] * 128;
        const float4* p4 = src + (size_t)sidx[j +  8] * 128;
        const float4* p5 = src + (size_t)sidx[j + 10] * 128;
        float4 vA0 = p0[lane], vB0 = p0[lane + 64];
        float4 vA1 = p1[lane], vB1 = p1[lane + 64];
        float4 vA2 = p2[lane], vB2 = p2[lane + 64];
        float4 vA3 = p3[lane], vB3 = p3[lane + 64];
        float4 vA4 = p4[lane], vB4 = p4[lane + 64];
        float4 vA5 = p5[lane], vB5 = p5[lane + 64];
        f4add(aA0, vA0); f4add(aB0, vB0);
        f4add(aA1, vA1); f4add(aB1, vB1);
        f4add(aA2, vA2); f4add(aB2, vB2);
        f4add(aA0, vA3); f4add(aB0, vB3);
        f4add(aA1, vA4); f4add(aB1, vB4);
        f4add(aA2, vA5); f4add(aB2, vB5);
    }
    for (; j < cnt; j += 2) {
        const float4* p = src + (size_t)sidx[j] * 128;
        f4add(aA0, p[lane]); f4add(aB0, p[lane + 64]);
    }
    f4add(aA0, aA1); f4add(aB0, aB1);
    f4add(aA0, aA2); f4add(aB0, aB2);

    // ---- combine the wave pair, store final (half,mod,class) sum ----
    if (par == 0) {
        cmb[mod][lane]      = aA0;
        cmb[mod][lane + 64] = aB0;
    }
    __syncthreads();
    if (par == 1) {
        float4 rA = cmb[mod][lane];      f4add(rA, aA0);
        float4 rB = cmb[mod][lane + 64]; f4add(rB, aB0);
        float4* dst = reinterpret_cast<float4*>(g_sum)
                    + (size_t)((h * 2 + mod) * NC + c) * 128;
        dst[lane]      = rA;
        dst[lane + 64] = rB;
    }
    if (tid == 0) g_cnt[h * NC + c] = cnt;
}

// ---------------------------------------------------------------------------
__device__ __forceinline__ float smooth_l1(float d) {
    d = fabsf(d);
    return d < 1.0f ? 0.5f * d * d : d - 0.5f;
}

// K2: combine the two row-halves, SmoothL1 weighted by count, reduce.
// Reads only 3.2 MB sums + 0.8 MB centers.
__global__ __launch_bounds__(256)
void k_loss(const float* __restrict__ centers, float* __restrict__ out) {
    __shared__ float scnt[NC];
    int t = threadIdx.x;
    for (int c = t; c < NC; c += 256)
        scnt[c] = (float)(g_cnt[c] + g_cnt[NC + c]);
    __syncthreads();

    const float4* ctr4 = reinterpret_cast<const float4*>(centers);
    const float4* s4   = reinterpret_cast<const float4*>(g_sum);
    const int NE4 = NEL / 4;          // 50560
    float val = 0.f;
    for (int g = blockIdx.x * 256 + t; g < NE4; g += gridDim.x * 256) {
        int cls = g >> 7;             // 128 float4 per class
        float cnt = scnt[cls];
        if (cnt > 0.f) {
            // layout: [h][mod][cls][FD]; mod0 = slabs 0,2; mod1 = slabs 1,3
            float4 s1 = s4[g];              f4add(s1, s4[2 * NE4 + g]);
            float4 s2 = s4[NE4 + g];        f4add(s2, s4[3 * NE4 + g]);
            float4 c4 = ctr4[g];
            float inv = 1.f / cnt;
            val += cnt * (smooth_l1(s1.x * inv - c4.x) + smooth_l1(s2.x * inv - c4.x)
                        + smooth_l1(s1.y * inv - c4.y) + smooth_l1(s2.y * inv - c4.y)
                        + smooth_l1(s1.z * inv - c4.z) + smooth_l1(s2.z * inv - c4.z)
                        + smooth_l1(s1.w * inv - c4.w) + smooth_l1(s2.w * inv - c4.w));
        }
    }

    for (int off = 32; off > 0; off >>= 1)
        val += __shfl_down(val, off, 64);
    __shared__ float wsum[4];
    int lane = t & 63, wid = t >> 6;
    if (lane == 0) wsum[wid] = val;
    __syncthreads();
    if (t == 0) {
        float sm = wsum[0] + wsum[1] + wsum[2] + wsum[3];
        atomicAdd(out, sm * 5.9604644775390625e-08f);  // 1/(N*D) = 2^-24
    }
}

extern "C" void kernel_launch(void* const* d_in, const int* in_sizes, int n_in,
                              void* d_out, int out_size, void* d_ws, size_t ws_size,
                              hipStream_t stream) {
    const float4* m1 = (const float4*)d_in[0];
    const float4* m2 = (const float4*)d_in[1];
    const float* centers = (const float*)d_in[2];
    const int* targets = (const int*)d_in[3];
    float* out = (float*)d_out;

    k_gather<<<NC * 2, 256, 0, stream>>>(m1, m2, targets, out);
    k_loss<<<200, 256, 0, stream>>>(centers, out);
}